// Round 7
// baseline (549.938 us; speedup 1.0000x reference)
//
#include <hip/hip_runtime.h>
#include <hip/hip_fp16.h>

// GraphConv: out = segment_sum(w * X[src] -> dst) @ W + b
// = gather of w * (X@W)[src] per dst (matmul distributes over segment-sum).
// Round 7: deterministic per-(block,bucket) segment binning (no global atomics,
// no zero-init, pure streaming flush) fused with the MFMA xw kernel; gather
// accumulates via LDS fp32 atomics (counting sort deleted); ovf folded in.
//
// V=100000, E=1250000, C=64, fp32 in/out.

constexpr int V = 100000;
constexpr int E = 1250000;
constexpr int C = 64;

constexpr int NBKT = 1024;        // dst buckets
constexpr int VB   = 98;          // vertices per bucket (1024*98 >= V)
constexpr int SEG  = 16;          // int2 slots per (block,bucket) segment: 1 header + 15 records
constexpr int BIN_BLOCKS = 256;
constexpr int EPB  = (E + BIN_BLOCKS - 1) / BIN_BLOCKS;   // 4883 edges per bin block
constexpr int STASH_CAP = 256;    // per-block spill list (expected ~0.04 used)

// ---------------- workspace layout (bytes) ----------------
constexpr size_t Y_OFF    = 0;            // V*C*2 = 12,800,000 (fp16)
constexpr size_t BIN_OFF  = 12800000;     // BIN_BLOCKS*NBKT*SEG*8 = 33,554,432
constexpr size_t OVFC_OFF = 46354432;     // BIN_BLOCKS*4 = 1,024
constexpr size_t OVFR_OFF = 46355456;     // BIN_BLOCKS*STASH_CAP*16 = 1,048,576
constexpr size_t WS_NEW   = 47404032;

using bf16x8 = __attribute__((ext_vector_type(8))) short;
using f32x4  = __attribute__((ext_vector_type(4))) float;

__device__ __forceinline__ short f2bf(float x) {          // RNE float->bf16 bits
    unsigned u = __float_as_uint(x);
    unsigned r = u + 0x7fffu + ((u >> 16) & 1u);
    return (short)(r >> 16);
}
__device__ __forceinline__ float bf2f(short h) {
    return __uint_as_float(((unsigned)(unsigned short)h) << 16);
}

// ---------------------------------------------------------------------------
// Fused kernel: blocks [0, XW_BLOCKS) compute Y = X@W via MFMA (16 waves, one
// 16-row chunk each).  Blocks [XW_BLOCKS, XW_BLOCKS+BIN_BLOCKS) bin their
// contiguous edge range into per-(block,bucket) LDS segments and flush as one
// contiguous 128KB stream.  No cross-block state, nothing needs zeroing.
// ---------------------------------------------------------------------------
constexpr int XW_BLOCKS = 391;            // 391*16 waves >= 6250 chunks

__global__ __launch_bounds__(1024) void xw_bin_kernel(const float* __restrict__ X,
                                                      const float* __restrict__ W,
                                                      const int*   __restrict__ esrc,
                                                      const int*   __restrict__ edst,
                                                      const float* __restrict__ ew,
                                                      __half* __restrict__ Y,
                                                      int2*  __restrict__ binned,
                                                      int*   __restrict__ ovfcnt,
                                                      int4*  __restrict__ ovfrec) {
    __shared__ alignas(16) char smem[139280];
    const int tid = threadIdx.x;

    if (blockIdx.x < XW_BLOCKS) {
        // ---------------- xw part (verified math, rounds 4-6) ----------------
        short* Whi = (short*)smem;                 // [64*72]
        short* Wlo = (short*)(smem + 9216 * 2);    // after Whi (9216 shorts)
        for (int idx = tid; idx < 4096; idx += 1024) {
            int k = idx >> 6, c = idx & 63;
            float w  = W[idx];
            short hi = f2bf(w);
            short lo = f2bf(w - bf2f(hi));
            Whi[c * 72 + k] = hi;
            Wlo[c * 72 + k] = lo;
        }
        __syncthreads();

        const int wave = tid >> 6;                 // 0..15
        const int lane = tid & 63;
        const int m = lane & 15;
        const int q = lane >> 4;

        const int chunk = blockIdx.x * 16 + wave;
        if (chunk >= V / 16) return;

        bf16x8 bhi[4][2], blo[4][2];
        #pragma unroll
        for (int t = 0; t < 4; ++t)
            #pragma unroll
            for (int h = 0; h < 2; ++h) {
                int o = (t * 16 + m) * 72 + h * 32 + q * 8;
                bhi[t][h] = *(const bf16x8*)&Whi[o];
                blo[t][h] = *(const bf16x8*)&Wlo[o];
            }

        const float* xp = X + (chunk * 16 + m) * 64 + q * 8;
        bf16x8 ahi[2], alo[2];
        #pragma unroll
        for (int h = 0; h < 2; ++h) {
            float4 f0 = *(const float4*)(xp + h * 32);
            float4 f1 = *(const float4*)(xp + h * 32 + 4);
            float f[8] = {f0.x, f0.y, f0.z, f0.w, f1.x, f1.y, f1.z, f1.w};
            #pragma unroll
            for (int j = 0; j < 8; ++j) {
                short hi = f2bf(f[j]);
                ahi[h][j] = hi;
                alo[h][j] = f2bf(f[j] - bf2f(hi));
            }
        }
        #pragma unroll
        for (int t = 0; t < 4; ++t) {
            f32x4 acc = {0.f, 0.f, 0.f, 0.f};
            #pragma unroll
            for (int h = 0; h < 2; ++h) {
                acc = __builtin_amdgcn_mfma_f32_16x16x32_bf16(ahi[h], bhi[t][h], acc, 0, 0, 0);
                acc = __builtin_amdgcn_mfma_f32_16x16x32_bf16(alo[h], bhi[t][h], acc, 0, 0, 0);
                acc = __builtin_amdgcn_mfma_f32_16x16x32_bf16(ahi[h], blo[t][h], acc, 0, 0, 0);
            }
            #pragma unroll
            for (int i = 0; i < 4; ++i) {
                int row = chunk * 16 + q * 4 + i;
                Y[row * 64 + t * 16 + m] = __float2half(acc[i]);
            }
        }
        return;
    }

    // ---------------- bin part ----------------
    int2* stage2 = (int2*)smem;                    // [NBKT*SEG]  131072 B
    int*  lcnt   = (int*)(smem + 131072);          // [NBKT]        4096 B
    int4* stash  = (int4*)(smem + 135168);         // [STASH_CAP]   4096 B
    int*  stashN = (int*)(smem + 139264);

    const int blk = blockIdx.x - XW_BLOCKS;        // 0..255
    for (int i = tid; i < NBKT; i += 1024) lcnt[i] = 0;
    if (tid == 0) *stashN = 0;
    __syncthreads();

    const int beg = blk * EPB;
    const int end = (beg + EPB < E) ? beg + EPB : E;
    for (int e = beg + tid; e < end; e += 1024) {
        int d = edst[e];
        int s = esrc[e];
        float w = ew[e];
        int bkt = d / VB;
        int ld  = d - bkt * VB;
        int pos = atomicAdd(&lcnt[bkt], 1);
        if (pos < SEG - 1) {
            stage2[bkt * SEG + 1 + pos] = make_int2((ld << 17) | s, __float_as_int(w));
        } else {
            int p = atomicAdd(stashN, 1);
            if (p < STASH_CAP) stash[p] = make_int4(s, d, __float_as_int(w), 0);
        }
    }
    __syncthreads();

    // headers
    for (int b = tid; b < NBKT; b += 1024) {
        int n = lcnt[b]; n = n < SEG - 1 ? n : SEG - 1;
        stage2[b * SEG] = make_int2(n, 0);
    }
    __syncthreads();

    // contiguous streaming flush: 128 KB per block
    {
        const int4* s4 = (const int4*)stage2;                          // 8192 int4
        int4* g4 = (int4*)(binned + (size_t)blk * NBKT * SEG);
        for (int k = tid; k < NBKT * SEG / 2; k += 1024) g4[k] = s4[k];
    }
    // spill list (unconditional count write -> no zeroing anywhere)
    int sn = *stashN; sn = sn < STASH_CAP ? sn : STASH_CAP;
    if (tid == 0) ovfcnt[blk] = sn;
    for (int k = tid; k < sn; k += 1024) ovfrec[blk * STASH_CAP + k] = stash[k];
}

// ---------------------------------------------------------------------------
// Bucket gather: one 512-thread block per bucket.  Waves stream the bucket's
// 256 segments (prefetching the next one), accumulate w*Y[src] into an LDS
// fp32 tile via ds_add_f32, then write out + bias.  No sort, no fp32 global
// atomics.  Spill records scanned at the end (expected empty).
// ---------------------------------------------------------------------------
__global__ __launch_bounds__(512) void bucket_gather_kernel(const int2* __restrict__ binned,
                                                            const int*  __restrict__ ovfcnt,
                                                            const int4* __restrict__ ovfrec,
                                                            const __half* __restrict__ Y,
                                                            const float* __restrict__ bias,
                                                            float* __restrict__ out) {
    __shared__ float tile[VB * C];                 // 25,088 B
    const int tid  = threadIdx.x;
    const int b    = blockIdx.x;
    const int lane = tid & 63;
    const int wv   = tid >> 6;                     // 0..7

    for (int i = tid; i < VB * C; i += 512) tile[i] = 0.f;
    __syncthreads();

    // stream segments blk = wv, wv+8, ..., 248  (prefetch next)
    int sb = wv;
    int2 rec = binned[((size_t)sb * NBKT + b) * SEG + (lane & 15)];
    while (sb < BIN_BLOCKS) {
        int sb2 = sb + 8;
        int2 nxt;
        if (sb2 < BIN_BLOCKS)
            nxt = binned[((size_t)sb2 * NBKT + b) * SEG + (lane & 15)];
        int cnt = __shfl(rec.x, 0);                // header
        int j = 1;
        for (; j + 3 <= cnt; j += 4) {             // 4 outstanding Y-row loads
            int rx0 = __shfl(rec.x, j),     wb0 = __shfl(rec.y, j);
            int rx1 = __shfl(rec.x, j + 1), wb1 = __shfl(rec.y, j + 1);
            int rx2 = __shfl(rec.x, j + 2), wb2 = __shfl(rec.y, j + 2);
            int rx3 = __shfl(rec.x, j + 3), wb3 = __shfl(rec.y, j + 3);
            float y0 = __half2float(Y[(rx0 & 0x1FFFF) * C + lane]);
            float y1 = __half2float(Y[(rx1 & 0x1FFFF) * C + lane]);
            float y2 = __half2float(Y[(rx2 & 0x1FFFF) * C + lane]);
            float y3 = __half2float(Y[(rx3 & 0x1FFFF) * C + lane]);
            atomicAdd(&tile[(rx0 >> 17) * C + lane], __int_as_float(wb0) * y0);
            atomicAdd(&tile[(rx1 >> 17) * C + lane], __int_as_float(wb1) * y1);
            atomicAdd(&tile[(rx2 >> 17) * C + lane], __int_as_float(wb2) * y2);
            atomicAdd(&tile[(rx3 >> 17) * C + lane], __int_as_float(wb3) * y3);
        }
        for (; j <= cnt; ++j) {
            int rx = __shfl(rec.x, j), wb = __shfl(rec.y, j);
            float yv = __half2float(Y[(rx & 0x1FFFF) * C + lane]);
            atomicAdd(&tile[(rx >> 17) * C + lane], __int_as_float(wb) * yv);
        }
        rec = nxt;
        sb = sb2;
    }

    // spill records (expected ~0 device-wide)
    const int lo = b * VB, hi = lo + VB;
    for (int blk = wv; blk < BIN_BLOCKS; blk += 8) {
        int n = ovfcnt[blk];
        for (int k = 0; k < n; ++k) {
            int4 r = ovfrec[blk * STASH_CAP + k];
            if (r.y >= lo && r.y < hi) {
                float yv = __half2float(Y[r.x * C + lane]);
                atomicAdd(&tile[(r.y - lo) * C + lane], __int_as_float(r.z) * yv);
            }
        }
    }
    __syncthreads();

    float bias_l = bias[lane];
    for (int ld = wv; ld < VB; ld += 8) {
        int v = b * VB + ld;
        if (v < V) out[v * C + lane] = tile[ld * C + lane] + bias_l;
    }
}

// ===========================================================================
// Fallback (ws too small): fp32 Y + bias init + fp32 atomic scatter (r1 path)
// ===========================================================================
__global__ __launch_bounds__(256) void xw_kernel(const float* __restrict__ X,
                                                 const float* __restrict__ W,
                                                 float* __restrict__ Y) {
    __shared__ float Ws[64][64];
    const float4* W4 = (const float4*)W;
    float4* Ws4 = (float4*)&Ws[0][0];
    #pragma unroll
    for (int i = 0; i < 4; ++i)
        Ws4[threadIdx.x + 256 * i] = W4[threadIdx.x + 256 * i];
    __syncthreads();
    const int wave = threadIdx.x >> 6;
    const int lane = threadIdx.x & 63;
    for (int row = blockIdx.x * 4 + wave; row < V; row += gridDim.x * 4) {
        float xv = X[row * C + lane];
        float acc = 0.f;
        #pragma unroll
        for (int k = 0; k < C; ++k)
            acc += __shfl(xv, k, 64) * Ws[k][lane];
        Y[row * C + lane] = acc;
    }
}

__global__ __launch_bounds__(256) void init_out_kernel(const float* __restrict__ b,
                                                       float4* __restrict__ out4) {
    int tid = blockIdx.x * 256 + threadIdx.x;
    const int n4 = V * (C / 4);
    if (tid < n4) {
        const float4* b4 = (const float4*)b;
        out4[tid] = b4[tid & 15];
    }
}

__global__ __launch_bounds__(256) void scatter_kernel(const int*   __restrict__ esrc,
                                                      const int*   __restrict__ edst,
                                                      const float* __restrict__ ew,
                                                      const float* __restrict__ Y,
                                                      float*       __restrict__ out) {
    unsigned tid = blockIdx.x * 256u + threadIdx.x;
    unsigned e = tid >> 4;
    if (e >= (unsigned)E) return;
    int g = (tid & 15) * 4;
    int   s  = esrc[e];
    int   d  = edst[e];
    float we = ew[e];
    float4 y = *(const float4*)(Y + s * C + g);
    float* o = out + (size_t)d * C + g;
    atomicAdd(o + 0, we * y.x);
    atomicAdd(o + 1, we * y.y);
    atomicAdd(o + 2, we * y.z);
    atomicAdd(o + 3, we * y.w);
}

extern "C" void kernel_launch(void* const* d_in, const int* in_sizes, int n_in,
                              void* d_out, int out_size, void* d_ws, size_t ws_size,
                              hipStream_t stream) {
    const float* X    = (const float*)d_in[0];
    const int*   esrc = (const int*)  d_in[1];
    const int*   edst = (const int*)  d_in[2];
    const float* ew   = (const float*)d_in[3];
    const float* W    = (const float*)d_in[4];
    const float* b    = (const float*)d_in[5];
    float* out = (float*)d_out;

    char* ws = (char*)d_ws;

    if (ws_size >= WS_NEW) {
        __half* Y     = (__half*)(ws + Y_OFF);
        int2*  binned = (int2*)(ws + BIN_OFF);
        int*   ovfcnt = (int*) (ws + OVFC_OFF);
        int4*  ovfrec = (int4*)(ws + OVFR_OFF);

        xw_bin_kernel<<<XW_BLOCKS + BIN_BLOCKS, 1024, 0, stream>>>(
            X, W, esrc, edst, ew, Y, binned, ovfcnt, ovfrec);
        bucket_gather_kernel<<<NBKT, 512, 0, stream>>>(
            binned, ovfcnt, ovfrec, Y, b, out);
    } else {
        float* Y = (float*)(ws + Y_OFF);
        xw_kernel<<<1024, 256, 0, stream>>>(X, W, Y);
        init_out_kernel<<<(V * (C / 4) + 255) / 256, 256, 0, stream>>>(b, (float4*)out);
        scatter_kernel<<<(E * 16 + 255) / 256, 256, 0, stream>>>(esrc, edst, ew, Y, out);
    }
}

// Round 8
// 145.083 us; speedup vs baseline: 3.7905x; 3.7905x over previous
//
#include <hip/hip_runtime.h>
#include <hip/hip_fp16.h>

// GraphConv: out = segment_sum(w * X[src] -> dst) @ W + b
// = gather of w * (X@W)[src] per dst (matmul distributes over segment-sum).
// Round 8: revert to round-6 structure (144us verified; round-7's shfl-fed
// gather serialized 13x). Deltas vs r6: gather ILP 8 (was 4), ovf launch
// folded into gather, bin FL=8 (68KB LDS -> 2 blocks/CU, 2x occupancy).
//
// V=100000, E=1250000, C=64, fp32 in/out.

constexpr int V = 100000;
constexpr int E = 1250000;
constexpr int C = 64;

constexpr int NBKT = 1024;        // dst buckets
constexpr int VB   = 98;          // vertices per bucket (1024*98 >= V)
constexpr int BCAP = 1536;        // records per bucket (mean 1221, +9 sigma)
constexpr int FL   = 8;           // LDS staging slots per bucket in bin_kernel
constexpr int OVF_CAP = 16384;

// ---------------- workspace layout (bytes) ----------------
constexpr size_t Y_OFF    = 0;           // V*C*2 = 12,800,000 (fp16)
constexpr size_t BIN_OFF  = 12800000;    // NBKT*BCAP*8 = 12,582,912
constexpr size_t GCNT_OFF = 25382912;    // NBKT*4 = 4,096
constexpr size_t OC_OFF   = 25387008;    // 16
constexpr size_t OVF_OFF  = 25387024;    // OVF_CAP*16 = 262,144
constexpr size_t WS_NEW   = 25649168;

using bf16x8 = __attribute__((ext_vector_type(8))) short;
using f32x4  = __attribute__((ext_vector_type(4))) float;

__device__ __forceinline__ short f2bf(float x) {          // RNE float->bf16 bits
    unsigned u = __float_as_uint(x);
    unsigned r = u + 0x7fffu + ((u >> 16) & 1u);
    return (short)(r >> 16);
}
__device__ __forceinline__ float bf2f(short h) {
    return __uint_as_float(((unsigned)(unsigned short)h) << 16);
}

// ---------------------------------------------------------------------------
// Fused: block 0 zeroes gcnt+oc; blocks [1,1+NBM) compute Y=X@W via MFMA.
// Per wave: one 16-row chunk; 3-term bf16 split (hi*hi + lo*hi + hi*lo).
// Y written fp16.  (Math verified rounds 4-6: absmax 0.0625.)
// ---------------------------------------------------------------------------
constexpr int ZB  = 1;
constexpr int NBM = 1563;                // 6252 waves >= 6250 chunks: 1 chunk/wave

__global__ __launch_bounds__(256) void zero_xw_kernel(const float* __restrict__ X,
                                                      const float* __restrict__ W,
                                                      __half* __restrict__ Y,
                                                      int* __restrict__ gcnt,
                                                      int* __restrict__ oc) {
    if (blockIdx.x < ZB) {
        int i = threadIdx.x;
        #pragma unroll
        for (int j = 0; j < NBKT / 256; ++j) gcnt[i + j * 256] = 0;
        if (i == 0) *oc = 0;
        return;
    }
    __shared__ short Whi[64 * 72];       // Wt[c][k], stride 72
    __shared__ short Wlo[64 * 72];
    for (int idx = threadIdx.x; idx < 4096; idx += 256) {
        int k = idx >> 6, c = idx & 63;
        float w  = W[idx];
        short hi = f2bf(w);
        short lo = f2bf(w - bf2f(hi));
        Whi[c * 72 + k] = hi;
        Wlo[c * 72 + k] = lo;
    }
    __syncthreads();

    const int wave = threadIdx.x >> 6;
    const int lane = threadIdx.x & 63;
    const int m = lane & 15;
    const int q = lane >> 4;

    bf16x8 bhi[4][2], blo[4][2];
    #pragma unroll
    for (int t = 0; t < 4; ++t)
        #pragma unroll
        for (int h = 0; h < 2; ++h) {
            int o = (t * 16 + m) * 72 + h * 32 + q * 8;
            bhi[t][h] = *(const bf16x8*)&Whi[o];
            blo[t][h] = *(const bf16x8*)&Wlo[o];
        }

    const int chunk = (blockIdx.x - ZB) * 4 + wave;
    if (chunk >= V / 16) return;
    {
        const float* xp = X + (chunk * 16 + m) * 64 + q * 8;
        bf16x8 ahi[2], alo[2];
        #pragma unroll
        for (int h = 0; h < 2; ++h) {
            float4 f0 = *(const float4*)(xp + h * 32);
            float4 f1 = *(const float4*)(xp + h * 32 + 4);
            float f[8] = {f0.x, f0.y, f0.z, f0.w, f1.x, f1.y, f1.z, f1.w};
            #pragma unroll
            for (int j = 0; j < 8; ++j) {
                short hi = f2bf(f[j]);
                ahi[h][j] = hi;
                alo[h][j] = f2bf(f[j] - bf2f(hi));
            }
        }
        #pragma unroll
        for (int t = 0; t < 4; ++t) {
            f32x4 acc = {0.f, 0.f, 0.f, 0.f};
            #pragma unroll
            for (int h = 0; h < 2; ++h) {
                acc = __builtin_amdgcn_mfma_f32_16x16x32_bf16(ahi[h], bhi[t][h], acc, 0, 0, 0);
                acc = __builtin_amdgcn_mfma_f32_16x16x32_bf16(alo[h], bhi[t][h], acc, 0, 0, 0);
                acc = __builtin_amdgcn_mfma_f32_16x16x32_bf16(ahi[h], blo[t][h], acc, 0, 0, 0);
            }
            #pragma unroll
            for (int i = 0; i < 4; ++i) {
                int row = chunk * 16 + q * 4 + i;
                Y[row * 64 + t * 16 + m] = __float2half(acc[i]);
            }
        }
    }
}

// ---------------------------------------------------------------------------
// Bin: 256 blocks x 1024 threads, 68KB LDS -> 2 blocks/CU (32 waves/CU).
// Records staged per-bucket in LDS, flushed at the end in contiguous bursts
// (one global atomic per bucket per block).  Record = (local_dst<<17|src, w).
// Staging overflow (mean 4.77 vs FL=8, ~1.5% of records) takes the direct
// global path with the shared gcnt cursor — same format, just unbatched.
// ---------------------------------------------------------------------------
constexpr int BIN_BLOCKS = 256;
constexpr int BIN_T      = 1024;

__global__ __launch_bounds__(BIN_T) void bin_kernel(const int*   __restrict__ esrc,
                                                    const int*   __restrict__ edst,
                                                    const float* __restrict__ ew,
                                                    int*  __restrict__ gcnt,
                                                    int2* __restrict__ binned,
                                                    int*  __restrict__ oc,
                                                    int4* __restrict__ ovf) {
    __shared__ int2 stage[NBKT][FL];     // 64 KB
    __shared__ int  lcnt[NBKT];          // 4 KB
    for (int i = threadIdx.x; i < NBKT; i += BIN_T) lcnt[i] = 0;
    __syncthreads();

    const int iters = (E + BIN_BLOCKS * BIN_T - 1) / (BIN_BLOCKS * BIN_T);   // 5
    for (int it = 0; it < iters; ++it) {
        int e = (it * BIN_BLOCKS + blockIdx.x) * BIN_T + threadIdx.x;
        if (e < E) {
            int d = edst[e];
            int s = esrc[e];
            float w = ew[e];
            int bkt = d / VB;
            int ld  = d - bkt * VB;
            int2 rec = make_int2((ld << 17) | s, __float_as_int(w));
            int pos = atomicAdd(&lcnt[bkt], 1);
            if (pos < FL) {
                stage[bkt][pos] = rec;
            } else {                                  // staging spill (~1.5%)
                int g = atomicAdd(&gcnt[bkt], 1);
                if (g < BCAP) binned[bkt * BCAP + g] = rec;
                else { int p = atomicAdd(oc, 1);
                       if (p < OVF_CAP) ovf[p] = make_int4(s, d, __float_as_int(w), 0); }
            }
        }
    }
    __syncthreads();
    // final flush: one thread per bucket — contiguous burst each
    for (int b = threadIdx.x; b < NBKT; b += BIN_T) {
        int n = lcnt[b]; n = n < FL ? n : FL;
        if (n > 0) {
            int g = atomicAdd(&gcnt[b], n);
            for (int i = 0; i < n; ++i) {
                int gi = g + i;
                int2 r = stage[b][i];
                if (gi < BCAP) binned[b * BCAP + gi] = r;
                else { int s = r.x & 0x1FFFF; int ld = r.x >> 17;
                       int p = atomicAdd(oc, 1);
                       if (p < OVF_CAP) ovf[p] = make_int4(s, b * VB + ld, r.y, 0); }
            }
        }
    }
}

// ---------------------------------------------------------------------------
// Bucket gather: one 512-thread block per bucket (27 KB LDS -> 4 blocks/CU,
// 32 waves/CU).  Counting-sort the bucket's records in LDS, then per-vertex
// register gather (wave per vertex, lane = channel, fp16 Y, fused bias) with
// 8 outstanding Y loads.  Overflow list folded in (expected empty).
// ---------------------------------------------------------------------------
__global__ __launch_bounds__(512) void bucket_gather_kernel(const int*  __restrict__ gcnt,
                                                            const int2* __restrict__ binned,
                                                            const int*  __restrict__ oc,
                                                            const int4* __restrict__ ovf,
                                                            const __half* __restrict__ Y,
                                                            const float* __restrict__ bias,
                                                            float* __restrict__ out) {
    __shared__ int2 raw[BCAP];           // 12 KB
    __shared__ int2 sorted[BCAP];        // 12 KB
    __shared__ int  cnt[VB];
    __shared__ int  pre[VB];
    __shared__ int  cur[VB];
    __shared__ int  buf[128];

    const int tid = threadIdx.x;
    const int b   = blockIdx.x;
    int n = gcnt[b]; n = n < BCAP ? n : BCAP;

    for (int i = tid; i < VB; i += 512) cnt[i] = 0;
    __syncthreads();

    const int2* src = binned + b * BCAP;
    for (int i = tid; i < n; i += 512) {
        int2 r = src[i];
        raw[i] = r;
        atomicAdd(&cnt[r.x >> 17], 1);
    }
    __syncthreads();

    // exclusive scan of cnt[0..VB) over first 128 threads (VB <= 128)
    int x = 0;
    if (tid < 128) { x = (tid < VB) ? cnt[tid] : 0; buf[tid] = x; }
    __syncthreads();
    #pragma unroll
    for (int ofs = 1; ofs < 128; ofs <<= 1) {
        int t = 0;
        if (tid < 128 && tid >= ofs) t = buf[tid - ofs];
        __syncthreads();
        if (tid < 128) buf[tid] += t;
        __syncthreads();
    }
    if (tid < VB) { int ex = buf[tid] - x; pre[tid] = ex; cur[tid] = ex; }
    __syncthreads();

    for (int i = tid; i < n; i += 512) {
        int2 r = raw[i];
        int ld = r.x >> 17;
        int p = atomicAdd(&cur[ld], 1);
        sorted[p] = r;
    }
    __syncthreads();

    const int lane = tid & 63;
    const int wv   = tid >> 6;           // 0..7
    float bias_l = bias[lane];
    int ovn = *oc; ovn = ovn < OVF_CAP ? ovn : OVF_CAP;   // expected 0

    for (int ld = wv; ld < VB; ld += 8) {
        int v = b * VB + ld;
        if (v >= V) break;
        int beg = pre[ld];
        int end = beg + cnt[ld];
        float acc = 0.f;
        int i = beg;
        for (; i + 8 <= end; i += 8) {           // 8 outstanding Y-row loads
            int2 r0 = sorted[i],     r1 = sorted[i + 1];
            int2 r2 = sorted[i + 2], r3 = sorted[i + 3];
            int2 r4 = sorted[i + 4], r5 = sorted[i + 5];
            int2 r6 = sorted[i + 6], r7 = sorted[i + 7];
            float y0 = __half2float(Y[(r0.x & 0x1FFFF) * C + lane]);
            float y1 = __half2float(Y[(r1.x & 0x1FFFF) * C + lane]);
            float y2 = __half2float(Y[(r2.x & 0x1FFFF) * C + lane]);
            float y3 = __half2float(Y[(r3.x & 0x1FFFF) * C + lane]);
            float y4 = __half2float(Y[(r4.x & 0x1FFFF) * C + lane]);
            float y5 = __half2float(Y[(r5.x & 0x1FFFF) * C + lane]);
            float y6 = __half2float(Y[(r6.x & 0x1FFFF) * C + lane]);
            float y7 = __half2float(Y[(r7.x & 0x1FFFF) * C + lane]);
            acc += __int_as_float(r0.y) * y0;
            acc += __int_as_float(r1.y) * y1;
            acc += __int_as_float(r2.y) * y2;
            acc += __int_as_float(r3.y) * y3;
            acc += __int_as_float(r4.y) * y4;
            acc += __int_as_float(r5.y) * y5;
            acc += __int_as_float(r6.y) * y6;
            acc += __int_as_float(r7.y) * y7;
        }
        for (; i + 4 <= end; i += 4) {
            int2 r0 = sorted[i], r1 = sorted[i + 1], r2 = sorted[i + 2], r3 = sorted[i + 3];
            float y0 = __half2float(Y[(r0.x & 0x1FFFF) * C + lane]);
            float y1 = __half2float(Y[(r1.x & 0x1FFFF) * C + lane]);
            float y2 = __half2float(Y[(r2.x & 0x1FFFF) * C + lane]);
            float y3 = __half2float(Y[(r3.x & 0x1FFFF) * C + lane]);
            acc += __int_as_float(r0.y) * y0;
            acc += __int_as_float(r1.y) * y1;
            acc += __int_as_float(r2.y) * y2;
            acc += __int_as_float(r3.y) * y3;
        }
        for (; i < end; ++i) {
            int2 rr = sorted[i];
            acc += __int_as_float(rr.y) * __half2float(Y[(rr.x & 0x1FFFF) * C + lane]);
        }
        // overflow backstop (ovn expected 0)
        for (int k = 0; k < ovn; ++k) {
            int4 rr = ovf[k];
            if (rr.y == v)
                acc += __int_as_float(rr.z) * __half2float(Y[rr.x * C + lane]);
        }
        out[v * C + lane] = acc + bias_l;
    }
}

// ===========================================================================
// Fallback (ws too small): fp32 Y + bias init + fp32 atomic scatter
// ===========================================================================
__global__ __launch_bounds__(256) void xw_kernel(const float* __restrict__ X,
                                                 const float* __restrict__ W,
                                                 float* __restrict__ Y) {
    __shared__ float Ws[64][64];
    const float4* W4 = (const float4*)W;
    float4* Ws4 = (float4*)&Ws[0][0];
    #pragma unroll
    for (int i = 0; i < 4; ++i)
        Ws4[threadIdx.x + 256 * i] = W4[threadIdx.x + 256 * i];
    __syncthreads();
    const int wave = threadIdx.x >> 6;
    const int lane = threadIdx.x & 63;
    for (int row = blockIdx.x * 4 + wave; row < V; row += gridDim.x * 4) {
        float xv = X[row * C + lane];
        float acc = 0.f;
        #pragma unroll
        for (int k = 0; k < C; ++k)
            acc += __shfl(xv, k, 64) * Ws[k][lane];
        Y[row * C + lane] = acc;
    }
}

__global__ __launch_bounds__(256) void init_out_kernel(const float* __restrict__ b,
                                                       float4* __restrict__ out4) {
    int tid = blockIdx.x * 256 + threadIdx.x;
    const int n4 = V * (C / 4);
    if (tid < n4) {
        const float4* b4 = (const float4*)b;
        out4[tid] = b4[tid & 15];
    }
}

__global__ __launch_bounds__(256) void scatter_kernel(const int*   __restrict__ esrc,
                                                      const int*   __restrict__ edst,
                                                      const float* __restrict__ ew,
                                                      const float* __restrict__ Y,
                                                      float*       __restrict__ out) {
    unsigned tid = blockIdx.x * 256u + threadIdx.x;
    unsigned e = tid >> 4;
    if (e >= (unsigned)E) return;
    int g = (tid & 15) * 4;
    int   s  = esrc[e];
    int   d  = edst[e];
    float we = ew[e];
    float4 y = *(const float4*)(Y + s * C + g);
    float* o = out + (size_t)d * C + g;
    atomicAdd(o + 0, we * y.x);
    atomicAdd(o + 1, we * y.y);
    atomicAdd(o + 2, we * y.z);
    atomicAdd(o + 3, we * y.w);
}

extern "C" void kernel_launch(void* const* d_in, const int* in_sizes, int n_in,
                              void* d_out, int out_size, void* d_ws, size_t ws_size,
                              hipStream_t stream) {
    const float* X    = (const float*)d_in[0];
    const int*   esrc = (const int*)  d_in[1];
    const int*   edst = (const int*)  d_in[2];
    const float* ew   = (const float*)d_in[3];
    const float* W    = (const float*)d_in[4];
    const float* b    = (const float*)d_in[5];
    float* out = (float*)d_out;

    char* ws = (char*)d_ws;

    if (ws_size >= WS_NEW) {
        __half* Y     = (__half*)(ws + Y_OFF);
        int2*  binned = (int2*)(ws + BIN_OFF);
        int*   gcnt   = (int*) (ws + GCNT_OFF);
        int*   oc     = (int*) (ws + OC_OFF);
        int4*  ovf    = (int4*)(ws + OVF_OFF);

        zero_xw_kernel<<<ZB + NBM, 256, 0, stream>>>(X, W, Y, gcnt, oc);
        bin_kernel<<<BIN_BLOCKS, BIN_T, 0, stream>>>(esrc, edst, ew, gcnt, binned, oc, ovf);
        bucket_gather_kernel<<<NBKT, 512, 0, stream>>>(gcnt, binned, oc, ovf, Y, b, out);
    } else {
        float* Y = (float*)(ws + Y_OFF);
        xw_kernel<<<1024, 256, 0, stream>>>(X, W, Y);
        init_out_kernel<<<(V * (C / 4) + 255) / 256, 256, 0, stream>>>(b, (float4*)out);
        scatter_kernel<<<(E * 16 + 255) / 256, 256, 0, stream>>>(esrc, edst, ew, Y, out);
    }
}

// Round 9
// 143.820 us; speedup vs baseline: 3.8238x; 1.0088x over previous
//
#include <hip/hip_runtime.h>
#include <hip/hip_fp16.h>

// GraphConv: out = segment_sum(w * X[src] -> dst) @ W + b
// = gather of w * (X@W)[src] per dst (matmul distributes over segment-sum).
// Round 9: r8 structure (verified 145us) with ONE change: BIN_BLOCKS 256->512.
// r8 lesson: FL=12->8 was useless because block count (256 = 1/CU), not LDS,
// capped bin occupancy. 512 blocks x 68KB = 2 blocks/CU = 32 waves/CU for the
// latency-bound edge-stream phase; spill rate also drops ~4% -> ~0.1%.
//
// V=100000, E=1250000, C=64, fp32 in/out.

constexpr int V = 100000;
constexpr int E = 1250000;
constexpr int C = 64;

constexpr int NBKT = 1024;        // dst buckets
constexpr int VB   = 98;          // vertices per bucket (1024*98 >= V)
constexpr int BCAP = 1536;        // records per bucket (mean 1221, +9 sigma)
constexpr int FL   = 8;           // LDS staging slots per bucket in bin_kernel
constexpr int OVF_CAP = 16384;

// ---------------- workspace layout (bytes) ----------------
constexpr size_t Y_OFF    = 0;           // V*C*2 = 12,800,000 (fp16)
constexpr size_t BIN_OFF  = 12800000;    // NBKT*BCAP*8 = 12,582,912
constexpr size_t GCNT_OFF = 25382912;    // NBKT*4 = 4,096
constexpr size_t OC_OFF   = 25387008;    // 16
constexpr size_t OVF_OFF  = 25387024;    // OVF_CAP*16 = 262,144
constexpr size_t WS_NEW   = 25649168;

using bf16x8 = __attribute__((ext_vector_type(8))) short;
using f32x4  = __attribute__((ext_vector_type(4))) float;

__device__ __forceinline__ short f2bf(float x) {          // RNE float->bf16 bits
    unsigned u = __float_as_uint(x);
    unsigned r = u + 0x7fffu + ((u >> 16) & 1u);
    return (short)(r >> 16);
}
__device__ __forceinline__ float bf2f(short h) {
    return __uint_as_float(((unsigned)(unsigned short)h) << 16);
}

// ---------------------------------------------------------------------------
// Fused: block 0 zeroes gcnt+oc; blocks [1,1+NBM) compute Y=X@W via MFMA.
// Per wave: one 16-row chunk; 3-term bf16 split (hi*hi + lo*hi + hi*lo).
// Y written fp16.  (Math verified rounds 4-8: absmax 0.0625.)
// ---------------------------------------------------------------------------
constexpr int ZB  = 1;
constexpr int NBM = 1563;                // 6252 waves >= 6250 chunks: 1 chunk/wave

__global__ __launch_bounds__(256) void zero_xw_kernel(const float* __restrict__ X,
                                                      const float* __restrict__ W,
                                                      __half* __restrict__ Y,
                                                      int* __restrict__ gcnt,
                                                      int* __restrict__ oc) {
    if (blockIdx.x < ZB) {
        int i = threadIdx.x;
        #pragma unroll
        for (int j = 0; j < NBKT / 256; ++j) gcnt[i + j * 256] = 0;
        if (i == 0) *oc = 0;
        return;
    }
    __shared__ short Whi[64 * 72];       // Wt[c][k], stride 72
    __shared__ short Wlo[64 * 72];
    for (int idx = threadIdx.x; idx < 4096; idx += 256) {
        int k = idx >> 6, c = idx & 63;
        float w  = W[idx];
        short hi = f2bf(w);
        short lo = f2bf(w - bf2f(hi));
        Whi[c * 72 + k] = hi;
        Wlo[c * 72 + k] = lo;
    }
    __syncthreads();

    const int wave = threadIdx.x >> 6;
    const int lane = threadIdx.x & 63;
    const int m = lane & 15;
    const int q = lane >> 4;

    bf16x8 bhi[4][2], blo[4][2];
    #pragma unroll
    for (int t = 0; t < 4; ++t)
        #pragma unroll
        for (int h = 0; h < 2; ++h) {
            int o = (t * 16 + m) * 72 + h * 32 + q * 8;
            bhi[t][h] = *(const bf16x8*)&Whi[o];
            blo[t][h] = *(const bf16x8*)&Wlo[o];
        }

    const int chunk = (blockIdx.x - ZB) * 4 + wave;
    if (chunk >= V / 16) return;
    {
        const float* xp = X + (chunk * 16 + m) * 64 + q * 8;
        bf16x8 ahi[2], alo[2];
        #pragma unroll
        for (int h = 0; h < 2; ++h) {
            float4 f0 = *(const float4*)(xp + h * 32);
            float4 f1 = *(const float4*)(xp + h * 32 + 4);
            float f[8] = {f0.x, f0.y, f0.z, f0.w, f1.x, f1.y, f1.z, f1.w};
            #pragma unroll
            for (int j = 0; j < 8; ++j) {
                short hi = f2bf(f[j]);
                ahi[h][j] = hi;
                alo[h][j] = f2bf(f[j] - bf2f(hi));
            }
        }
        #pragma unroll
        for (int t = 0; t < 4; ++t) {
            f32x4 acc = {0.f, 0.f, 0.f, 0.f};
            #pragma unroll
            for (int h = 0; h < 2; ++h) {
                acc = __builtin_amdgcn_mfma_f32_16x16x32_bf16(ahi[h], bhi[t][h], acc, 0, 0, 0);
                acc = __builtin_amdgcn_mfma_f32_16x16x32_bf16(alo[h], bhi[t][h], acc, 0, 0, 0);
                acc = __builtin_amdgcn_mfma_f32_16x16x32_bf16(ahi[h], blo[t][h], acc, 0, 0, 0);
            }
            #pragma unroll
            for (int i = 0; i < 4; ++i) {
                int row = chunk * 16 + q * 4 + i;
                Y[row * 64 + t * 16 + m] = __float2half(acc[i]);
            }
        }
    }
}

// ---------------------------------------------------------------------------
// Bin: 512 blocks x 1024 threads, 68KB LDS -> 2 blocks/CU = 32 waves/CU.
// Records staged per-bucket in LDS, flushed at the end in contiguous bursts
// (one global atomic per bucket per block).  Record = (local_dst<<17|src, w).
// Per-(block,bucket) mean 2.38 -> staging spill ~0.1% (direct global path).
// ---------------------------------------------------------------------------
constexpr int BIN_BLOCKS = 512;
constexpr int BIN_T      = 1024;

__global__ __launch_bounds__(BIN_T) void bin_kernel(const int*   __restrict__ esrc,
                                                    const int*   __restrict__ edst,
                                                    const float* __restrict__ ew,
                                                    int*  __restrict__ gcnt,
                                                    int2* __restrict__ binned,
                                                    int*  __restrict__ oc,
                                                    int4* __restrict__ ovf) {
    __shared__ int2 stage[NBKT][FL];     // 64 KB
    __shared__ int  lcnt[NBKT];          // 4 KB
    for (int i = threadIdx.x; i < NBKT; i += BIN_T) lcnt[i] = 0;
    __syncthreads();

    const int iters = (E + BIN_BLOCKS * BIN_T - 1) / (BIN_BLOCKS * BIN_T);   // 3
    for (int it = 0; it < iters; ++it) {
        int e = (it * BIN_BLOCKS + blockIdx.x) * BIN_T + threadIdx.x;
        if (e < E) {
            int d = edst[e];
            int s = esrc[e];
            float w = ew[e];
            int bkt = d / VB;
            int ld  = d - bkt * VB;
            int2 rec = make_int2((ld << 17) | s, __float_as_int(w));
            int pos = atomicAdd(&lcnt[bkt], 1);
            if (pos < FL) {
                stage[bkt][pos] = rec;
            } else {                                  // staging spill (~0.1%)
                int g = atomicAdd(&gcnt[bkt], 1);
                if (g < BCAP) binned[bkt * BCAP + g] = rec;
                else { int p = atomicAdd(oc, 1);
                       if (p < OVF_CAP) ovf[p] = make_int4(s, d, __float_as_int(w), 0); }
            }
        }
    }
    __syncthreads();
    // final flush: one thread per bucket — contiguous burst each
    for (int b = threadIdx.x; b < NBKT; b += BIN_T) {
        int n = lcnt[b]; n = n < FL ? n : FL;
        if (n > 0) {
            int g = atomicAdd(&gcnt[b], n);
            for (int i = 0; i < n; ++i) {
                int gi = g + i;
                int2 r = stage[b][i];
                if (gi < BCAP) binned[b * BCAP + gi] = r;
                else { int s = r.x & 0x1FFFF; int ld = r.x >> 17;
                       int p = atomicAdd(oc, 1);
                       if (p < OVF_CAP) ovf[p] = make_int4(s, b * VB + ld, r.y, 0); }
            }
        }
    }
}

// ---------------------------------------------------------------------------
// Bucket gather: one 512-thread block per bucket (27 KB LDS -> 4 blocks/CU,
// 32 waves/CU).  Counting-sort the bucket's records in LDS, then per-vertex
// register gather (wave per vertex, lane = channel, fp16 Y, fused bias) with
// 8 outstanding Y loads.  Overflow list folded in (expected empty).
// ---------------------------------------------------------------------------
__global__ __launch_bounds__(512) void bucket_gather_kernel(const int*  __restrict__ gcnt,
                                                            const int2* __restrict__ binned,
                                                            const int*  __restrict__ oc,
                                                            const int4* __restrict__ ovf,
                                                            const __half* __restrict__ Y,
                                                            const float* __restrict__ bias,
                                                            float* __restrict__ out) {
    __shared__ int2 raw[BCAP];           // 12 KB
    __shared__ int2 sorted[BCAP];        // 12 KB
    __shared__ int  cnt[VB];
    __shared__ int  pre[VB];
    __shared__ int  cur[VB];
    __shared__ int  buf[128];

    const int tid = threadIdx.x;
    const int b   = blockIdx.x;
    int n = gcnt[b]; n = n < BCAP ? n : BCAP;

    for (int i = tid; i < VB; i += 512) cnt[i] = 0;
    __syncthreads();

    const int2* src = binned + b * BCAP;
    for (int i = tid; i < n; i += 512) {
        int2 r = src[i];
        raw[i] = r;
        atomicAdd(&cnt[r.x >> 17], 1);
    }
    __syncthreads();

    // exclusive scan of cnt[0..VB) over first 128 threads (VB <= 128)
    int x = 0;
    if (tid < 128) { x = (tid < VB) ? cnt[tid] : 0; buf[tid] = x; }
    __syncthreads();
    #pragma unroll
    for (int ofs = 1; ofs < 128; ofs <<= 1) {
        int t = 0;
        if (tid < 128 && tid >= ofs) t = buf[tid - ofs];
        __syncthreads();
        if (tid < 128) buf[tid] += t;
        __syncthreads();
    }
    if (tid < VB) { int ex = buf[tid] - x; pre[tid] = ex; cur[tid] = ex; }
    __syncthreads();

    for (int i = tid; i < n; i += 512) {
        int2 r = raw[i];
        int ld = r.x >> 17;
        int p = atomicAdd(&cur[ld], 1);
        sorted[p] = r;
    }
    __syncthreads();

    const int lane = tid & 63;
    const int wv   = tid >> 6;           // 0..7
    float bias_l = bias[lane];
    int ovn = *oc; ovn = ovn < OVF_CAP ? ovn : OVF_CAP;   // expected 0

    for (int ld = wv; ld < VB; ld += 8) {
        int v = b * VB + ld;
        if (v >= V) break;
        int beg = pre[ld];
        int end = beg + cnt[ld];
        float acc = 0.f;
        int i = beg;
        for (; i + 8 <= end; i += 8) {           // 8 outstanding Y-row loads
            int2 r0 = sorted[i],     r1 = sorted[i + 1];
            int2 r2 = sorted[i + 2], r3 = sorted[i + 3];
            int2 r4 = sorted[i + 4], r5 = sorted[i + 5];
            int2 r6 = sorted[i + 6], r7 = sorted[i + 7];
            float y0 = __half2float(Y[(r0.x & 0x1FFFF) * C + lane]);
            float y1 = __half2float(Y[(r1.x & 0x1FFFF) * C + lane]);
            float y2 = __half2float(Y[(r2.x & 0x1FFFF) * C + lane]);
            float y3 = __half2float(Y[(r3.x & 0x1FFFF) * C + lane]);
            float y4 = __half2float(Y[(r4.x & 0x1FFFF) * C + lane]);
            float y5 = __half2float(Y[(r5.x & 0x1FFFF) * C + lane]);
            float y6 = __half2float(Y[(r6.x & 0x1FFFF) * C + lane]);
            float y7 = __half2float(Y[(r7.x & 0x1FFFF) * C + lane]);
            acc += __int_as_float(r0.y) * y0;
            acc += __int_as_float(r1.y) * y1;
            acc += __int_as_float(r2.y) * y2;
            acc += __int_as_float(r3.y) * y3;
            acc += __int_as_float(r4.y) * y4;
            acc += __int_as_float(r5.y) * y5;
            acc += __int_as_float(r6.y) * y6;
            acc += __int_as_float(r7.y) * y7;
        }
        for (; i + 4 <= end; i += 4) {
            int2 r0 = sorted[i], r1 = sorted[i + 1], r2 = sorted[i + 2], r3 = sorted[i + 3];
            float y0 = __half2float(Y[(r0.x & 0x1FFFF) * C + lane]);
            float y1 = __half2float(Y[(r1.x & 0x1FFFF) * C + lane]);
            float y2 = __half2float(Y[(r2.x & 0x1FFFF) * C + lane]);
            float y3 = __half2float(Y[(r3.x & 0x1FFFF) * C + lane]);
            acc += __int_as_float(r0.y) * y0;
            acc += __int_as_float(r1.y) * y1;
            acc += __int_as_float(r2.y) * y2;
            acc += __int_as_float(r3.y) * y3;
        }
        for (; i < end; ++i) {
            int2 rr = sorted[i];
            acc += __int_as_float(rr.y) * __half2float(Y[(rr.x & 0x1FFFF) * C + lane]);
        }
        // overflow backstop (ovn expected 0)
        for (int k = 0; k < ovn; ++k) {
            int4 rr = ovf[k];
            if (rr.y == v)
                acc += __int_as_float(rr.z) * __half2float(Y[rr.x * C + lane]);
        }
        out[v * C + lane] = acc + bias_l;
    }
}

// ===========================================================================
// Fallback (ws too small): fp32 Y + bias init + fp32 atomic scatter
// ===========================================================================
__global__ __launch_bounds__(256) void xw_kernel(const float* __restrict__ X,
                                                 const float* __restrict__ W,
                                                 float* __restrict__ Y) {
    __shared__ float Ws[64][64];
    const float4* W4 = (const float4*)W;
    float4* Ws4 = (float4*)&Ws[0][0];
    #pragma unroll
    for (int i = 0; i < 4; ++i)
        Ws4[threadIdx.x + 256 * i] = W4[threadIdx.x + 256 * i];
    __syncthreads();
    const int wave = threadIdx.x >> 6;
    const int lane = threadIdx.x & 63;
    for (int row = blockIdx.x * 4 + wave; row < V; row += gridDim.x * 4) {
        float xv = X[row * C + lane];
        float acc = 0.f;
        #pragma unroll
        for (int k = 0; k < C; ++k)
            acc += __shfl(xv, k, 64) * Ws[k][lane];
        Y[row * C + lane] = acc;
    }
}

__global__ __launch_bounds__(256) void init_out_kernel(const float* __restrict__ b,
                                                       float4* __restrict__ out4) {
    int tid = blockIdx.x * 256 + threadIdx.x;
    const int n4 = V * (C / 4);
    if (tid < n4) {
        const float4* b4 = (const float4*)b;
        out4[tid] = b4[tid & 15];
    }
}

__global__ __launch_bounds__(256) void scatter_kernel(const int*   __restrict__ esrc,
                                                      const int*   __restrict__ edst,
                                                      const float* __restrict__ ew,
                                                      const float* __restrict__ Y,
                                                      float*       __restrict__ out) {
    unsigned tid = blockIdx.x * 256u + threadIdx.x;
    unsigned e = tid >> 4;
    if (e >= (unsigned)E) return;
    int g = (tid & 15) * 4;
    int   s  = esrc[e];
    int   d  = edst[e];
    float we = ew[e];
    float4 y = *(const float4*)(Y + s * C + g);
    float* o = out + (size_t)d * C + g;
    atomicAdd(o + 0, we * y.x);
    atomicAdd(o + 1, we * y.y);
    atomicAdd(o + 2, we * y.z);
    atomicAdd(o + 3, we * y.w);
}

extern "C" void kernel_launch(void* const* d_in, const int* in_sizes, int n_in,
                              void* d_out, int out_size, void* d_ws, size_t ws_size,
                              hipStream_t stream) {
    const float* X    = (const float*)d_in[0];
    const int*   esrc = (const int*)  d_in[1];
    const int*   edst = (const int*)  d_in[2];
    const float* ew   = (const float*)d_in[3];
    const float* W    = (const float*)d_in[4];
    const float* b    = (const float*)d_in[5];
    float* out = (float*)d_out;

    char* ws = (char*)d_ws;

    if (ws_size >= WS_NEW) {
        __half* Y     = (__half*)(ws + Y_OFF);
        int2*  binned = (int2*)(ws + BIN_OFF);
        int*   gcnt   = (int*) (ws + GCNT_OFF);
        int*   oc     = (int*) (ws + OC_OFF);
        int4*  ovf    = (int4*)(ws + OVF_OFF);

        zero_xw_kernel<<<ZB + NBM, 256, 0, stream>>>(X, W, Y, gcnt, oc);
        bin_kernel<<<BIN_BLOCKS, BIN_T, 0, stream>>>(esrc, edst, ew, gcnt, binned, oc, ovf);
        bucket_gather_kernel<<<NBKT, 512, 0, stream>>>(gcnt, binned, oc, ovf, Y, b, out);
    } else {
        float* Y = (float*)(ws + Y_OFF);
        xw_kernel<<<1024, 256, 0, stream>>>(X, W, Y);
        init_out_kernel<<<(V * (C / 4) + 255) / 256, 256, 0, stream>>>(b, (float4*)out);
        scatter_kernel<<<(E * 16 + 255) / 256, 256, 0, stream>>>(esrc, edst, ew, Y, out);
    }
}